// Round 1
// baseline (253.947 us; speedup 1.0000x reference)
//
#include <hip/hip_runtime.h>
#include <math.h>

#define NSEG 4096
#define HDIM 256

// One block per segment. batch[] is sorted, so segment s occupies rows
// [lower_bound(batch,s), lower_bound(batch,s+1)).
// Phase A: segment mean (memory-bound, float4 coalesced streaming).
// Phase B: out_row = gelu(pooled @ W1 + b1) @ W2 + b2 (fp32 vector ALU,
//          weights are 512KB total -> L2-resident).
__global__ __launch_bounds__(256)
void fused_pool_mlp(const float* __restrict__ x,
                    const int*   __restrict__ batch,
                    const float* __restrict__ W1,
                    const float* __restrict__ b1,
                    const float* __restrict__ W2,
                    const float* __restrict__ b2,
                    float*       __restrict__ out,
                    int N)
{
    const int s    = blockIdx.x;
    const int tid  = threadIdx.x;
    const int wave = tid >> 6;   // 0..3
    const int lane = tid & 63;   // 0..63

    __shared__ int s_r0, s_r1;
    if (tid == 0) {
        int lo = 0, hi = N;
        while (lo < hi) { int m = (lo + hi) >> 1; if (batch[m] < s)     lo = m + 1; else hi = m; }
        s_r0 = lo;
        hi = N;
        while (lo < hi) { int m = (lo + hi) >> 1; if (batch[m] < s + 1) lo = m + 1; else hi = m; }
        s_r1 = lo;
    }
    __syncthreads();
    const int r0 = s_r0, r1 = s_r1;

    // ---- Phase A: sum rows [r0, r1). Wave w takes rows r0+w, r0+w+4, ...
    // Lane l accumulates columns [4l, 4l+4). 2-deep unroll for load ILP.
    float4 a0 = make_float4(0.f, 0.f, 0.f, 0.f);
    float4 a1 = make_float4(0.f, 0.f, 0.f, 0.f);
    int r = r0 + wave;
    for (; r + 4 < r1; r += 8) {
        const float4 v0 = *reinterpret_cast<const float4*>(x + (size_t)r       * HDIM + lane * 4);
        const float4 v1 = *reinterpret_cast<const float4*>(x + (size_t)(r + 4) * HDIM + lane * 4);
        a0.x += v0.x; a0.y += v0.y; a0.z += v0.z; a0.w += v0.w;
        a1.x += v1.x; a1.y += v1.y; a1.z += v1.z; a1.w += v1.w;
    }
    if (r < r1) {
        const float4 v0 = *reinterpret_cast<const float4*>(x + (size_t)r * HDIM + lane * 4);
        a0.x += v0.x; a0.y += v0.y; a0.z += v0.z; a0.w += v0.w;
    }
    a0.x += a1.x; a0.y += a1.y; a0.z += a1.z; a0.w += a1.w;

    // ---- Cross-wave reduce in LDS -> pooled row (256 floats)
    __shared__ float4 part4[4][64];
    __shared__ float  pooled[HDIM];
    __shared__ float  hbuf[HDIM];
    part4[wave][lane] = a0;
    __syncthreads();

    const float* pf = reinterpret_cast<const float*>(part4);
    float sum = (pf[tid] + pf[256 + tid]) + (pf[512 + tid] + pf[768 + tid]);
    const int   cnt  = r1 - r0;
    const float cntf = (float)(cnt > 1 ? cnt : 1);
    pooled[tid] = sum / cntf;
    __syncthreads();

    // ---- Phase B1: z[t] = pooled . W1[:,t] + b1[t]; h = exact gelu(z)
    float c0 = 0.f, c1 = 0.f, c2 = 0.f, c3 = 0.f;
    for (int k = 0; k < HDIM; k += 4) {
        c0 = fmaf(pooled[k + 0], W1[(k + 0) * HDIM + tid], c0);
        c1 = fmaf(pooled[k + 1], W1[(k + 1) * HDIM + tid], c1);
        c2 = fmaf(pooled[k + 2], W1[(k + 2) * HDIM + tid], c2);
        c3 = fmaf(pooled[k + 3], W1[(k + 3) * HDIM + tid], c3);
    }
    const float z = (c0 + c1) + (c2 + c3) + b1[tid];
    // exact GELU: 0.5 * z * (1 + erf(z / sqrt(2)))
    hbuf[tid] = 0.5f * z * (1.0f + erff(z * 0.7071067811865476f));
    __syncthreads();

    // ---- Phase B2: out[t] = h . W2[:,t] + b2[t]
    c0 = c1 = c2 = c3 = 0.f;
    for (int k = 0; k < HDIM; k += 4) {
        c0 = fmaf(hbuf[k + 0], W2[(k + 0) * HDIM + tid], c0);
        c1 = fmaf(hbuf[k + 1], W2[(k + 1) * HDIM + tid], c1);
        c2 = fmaf(hbuf[k + 2], W2[(k + 2) * HDIM + tid], c2);
        c3 = fmaf(hbuf[k + 3], W2[(k + 3) * HDIM + tid], c3);
    }
    out[(size_t)s * HDIM + tid] = (c0 + c1) + (c2 + c3) + b2[tid];
}

extern "C" void kernel_launch(void* const* d_in, const int* in_sizes, int n_in,
                              void* d_out, int out_size, void* d_ws, size_t ws_size,
                              hipStream_t stream) {
    // setup_inputs order: x, edge_index, edge_type, batch, W1, b1, W2, b2
    const float* x     = (const float*)d_in[0];
    const int*   batch = (const int*)  d_in[3];
    const float* W1    = (const float*)d_in[4];
    const float* b1    = (const float*)d_in[5];
    const float* W2    = (const float*)d_in[6];
    const float* b2    = (const float*)d_in[7];
    float* out = (float*)d_out;
    const int N = in_sizes[3];   // 1048576 rows

    hipLaunchKernelGGL(fused_pool_mlp, dim3(NSEG), dim3(256), 0, stream,
                       x, batch, W1, b1, W2, b2, out, N);
}

// Round 2
// 245.669 us; speedup vs baseline: 1.0337x; 1.0337x over previous
//
#include <hip/hip_runtime.h>
#include <math.h>

#define NSEG 4096
#define HDIM 256
#define SPB  16   // segments per MLP block

__device__ __forceinline__ float gelu_exact(float z) {
    return 0.5f * z * (1.0f + erff(z * 0.7071067811865476f));
}

// ---------- kernel 1: offs[i] = lower_bound(batch, i), i in [0, NSEG] ----------
__global__ __launch_bounds__(256)
void seg_offsets_kernel(const int* __restrict__ batch, int* __restrict__ offs, int N) {
    int i = blockIdx.x * 256 + threadIdx.x;
    if (i > NSEG) return;
    int lo = 0, hi = N;
    while (lo < hi) { int m = (lo + hi) >> 1; if (batch[m] < i) lo = m + 1; else hi = m; }
    offs[i] = lo;
}

// ---------- kernel 2: pooled[s][:] = mean of x rows [offs[s], offs[s+1]) ----------
__global__ __launch_bounds__(256)
void pool_kernel(const float* __restrict__ x, const int* __restrict__ offs,
                 float* __restrict__ pooled) {
    const int s    = blockIdx.x;
    const int tid  = threadIdx.x;
    const int wave = tid >> 6;
    const int lane = tid & 63;
    const int r0 = offs[s], r1 = offs[s + 1];

    float4 a0 = make_float4(0.f,0.f,0.f,0.f), a1 = a0, a2 = a0, a3 = a0;
    const float* colp = x + (size_t)lane * 4;
    int r = r0 + wave;
    // wave w owns rows r0+w, r0+w+4, ... ; 4-deep unroll = 4 loads in flight/lane
    for (; r + 12 < r1; r += 16) {
        float4 v0 = *(const float4*)(colp + (size_t)(r     ) * HDIM);
        float4 v1 = *(const float4*)(colp + (size_t)(r +  4) * HDIM);
        float4 v2 = *(const float4*)(colp + (size_t)(r +  8) * HDIM);
        float4 v3 = *(const float4*)(colp + (size_t)(r + 12) * HDIM);
        a0.x += v0.x; a0.y += v0.y; a0.z += v0.z; a0.w += v0.w;
        a1.x += v1.x; a1.y += v1.y; a1.z += v1.z; a1.w += v1.w;
        a2.x += v2.x; a2.y += v2.y; a2.z += v2.z; a2.w += v2.w;
        a3.x += v3.x; a3.y += v3.y; a3.z += v3.z; a3.w += v3.w;
    }
    for (; r < r1; r += 4) {
        float4 v0 = *(const float4*)(colp + (size_t)r * HDIM);
        a0.x += v0.x; a0.y += v0.y; a0.z += v0.z; a0.w += v0.w;
    }
    a0.x += a1.x + a2.x + a3.x;
    a0.y += a1.y + a2.y + a3.y;
    a0.z += a1.z + a2.z + a3.z;
    a0.w += a1.w + a2.w + a3.w;

    __shared__ float part[4][HDIM];
    *(float4*)&part[wave][lane * 4] = a0;
    __syncthreads();
    float sum = (part[0][tid] + part[1][tid]) + (part[2][tid] + part[3][tid]);
    const int cnt = r1 - r0;
    pooled[(size_t)s * HDIM + tid] = sum / (float)(cnt > 1 ? cnt : 1);
}

// ---------- kernel 3: out = gelu(P @ W1 + b1) @ W2 + b2, 16 segments/block ----------
// 4 waves x 4 rows each; lane l owns cols 4l..4l+3 -> 4x4 register tile/thread.
// W1/W2 rows read coalesced (L2-resident, 16x reuse vs 1 block/segment).
__global__ __launch_bounds__(256)
void mlp_kernel(const float* __restrict__ pooled,
                const float* __restrict__ W1, const float* __restrict__ b1,
                const float* __restrict__ W2, const float* __restrict__ b2,
                float* __restrict__ out) {
    const int s0   = blockIdx.x * SPB;
    const int tid  = threadIdx.x;
    const int row0 = (tid >> 6) * 4;   // wave -> 4 rows
    const int col0 = (tid & 63) * 4;   // lane -> 4 cols

    __shared__ float P[SPB][HDIM];
    __shared__ float Hs[SPB][HDIM];

    #pragma unroll
    for (int i = 0; i < SPB; ++i)
        P[i][tid] = pooled[(size_t)(s0 + i) * HDIM + tid];
    __syncthreads();

    // ---- layer 1
    float acc[4][4];
    #pragma unroll
    for (int i = 0; i < 4; ++i)
        #pragma unroll
        for (int j = 0; j < 4; ++j) acc[i][j] = 0.f;

    for (int k = 0; k < HDIM; k += 4) {
        const float4 w0 = *(const float4*)(W1 + (size_t)(k + 0) * HDIM + col0);
        const float4 w1 = *(const float4*)(W1 + (size_t)(k + 1) * HDIM + col0);
        const float4 w2 = *(const float4*)(W1 + (size_t)(k + 2) * HDIM + col0);
        const float4 w3 = *(const float4*)(W1 + (size_t)(k + 3) * HDIM + col0);
        #pragma unroll
        for (int i = 0; i < 4; ++i) {
            const float4 p = *(const float4*)(&P[row0 + i][k]);   // wave-broadcast
            acc[i][0] = fmaf(p.x, w0.x, acc[i][0]); acc[i][1] = fmaf(p.x, w0.y, acc[i][1]);
            acc[i][2] = fmaf(p.x, w0.z, acc[i][2]); acc[i][3] = fmaf(p.x, w0.w, acc[i][3]);
            acc[i][0] = fmaf(p.y, w1.x, acc[i][0]); acc[i][1] = fmaf(p.y, w1.y, acc[i][1]);
            acc[i][2] = fmaf(p.y, w1.z, acc[i][2]); acc[i][3] = fmaf(p.y, w1.w, acc[i][3]);
            acc[i][0] = fmaf(p.z, w2.x, acc[i][0]); acc[i][1] = fmaf(p.z, w2.y, acc[i][1]);
            acc[i][2] = fmaf(p.z, w2.z, acc[i][2]); acc[i][3] = fmaf(p.z, w2.w, acc[i][3]);
            acc[i][0] = fmaf(p.w, w3.x, acc[i][0]); acc[i][1] = fmaf(p.w, w3.y, acc[i][1]);
            acc[i][2] = fmaf(p.w, w3.z, acc[i][2]); acc[i][3] = fmaf(p.w, w3.w, acc[i][3]);
        }
    }
    {
        const float4 bb = *(const float4*)(b1 + col0);
        const float bv[4] = {bb.x, bb.y, bb.z, bb.w};
        #pragma unroll
        for (int i = 0; i < 4; ++i) {
            float4 h;
            h.x = gelu_exact(acc[i][0] + bv[0]);
            h.y = gelu_exact(acc[i][1] + bv[1]);
            h.z = gelu_exact(acc[i][2] + bv[2]);
            h.w = gelu_exact(acc[i][3] + bv[3]);
            *(float4*)&Hs[row0 + i][col0] = h;
        }
    }
    __syncthreads();

    // ---- layer 2
    #pragma unroll
    for (int i = 0; i < 4; ++i)
        #pragma unroll
        for (int j = 0; j < 4; ++j) acc[i][j] = 0.f;

    for (int k = 0; k < HDIM; k += 4) {
        const float4 w0 = *(const float4*)(W2 + (size_t)(k + 0) * HDIM + col0);
        const float4 w1 = *(const float4*)(W2 + (size_t)(k + 1) * HDIM + col0);
        const float4 w2 = *(const float4*)(W2 + (size_t)(k + 2) * HDIM + col0);
        const float4 w3 = *(const float4*)(W2 + (size_t)(k + 3) * HDIM + col0);
        #pragma unroll
        for (int i = 0; i < 4; ++i) {
            const float4 p = *(const float4*)(&Hs[row0 + i][k]);
            acc[i][0] = fmaf(p.x, w0.x, acc[i][0]); acc[i][1] = fmaf(p.x, w0.y, acc[i][1]);
            acc[i][2] = fmaf(p.x, w0.z, acc[i][2]); acc[i][3] = fmaf(p.x, w0.w, acc[i][3]);
            acc[i][0] = fmaf(p.y, w1.x, acc[i][0]); acc[i][1] = fmaf(p.y, w1.y, acc[i][1]);
            acc[i][2] = fmaf(p.y, w1.z, acc[i][2]); acc[i][3] = fmaf(p.y, w1.w, acc[i][3]);
            acc[i][0] = fmaf(p.z, w2.x, acc[i][0]); acc[i][1] = fmaf(p.z, w2.y, acc[i][1]);
            acc[i][2] = fmaf(p.z, w2.z, acc[i][2]); acc[i][3] = fmaf(p.z, w2.w, acc[i][3]);
            acc[i][0] = fmaf(p.w, w3.x, acc[i][0]); acc[i][1] = fmaf(p.w, w3.y, acc[i][1]);
            acc[i][2] = fmaf(p.w, w3.z, acc[i][2]); acc[i][3] = fmaf(p.w, w3.w, acc[i][3]);
        }
    }
    {
        const float4 bb = *(const float4*)(b2 + col0);
        const float bv[4] = {bb.x, bb.y, bb.z, bb.w};
        #pragma unroll
        for (int i = 0; i < 4; ++i) {
            float4 o;
            o.x = acc[i][0] + bv[0];
            o.y = acc[i][1] + bv[1];
            o.z = acc[i][2] + bv[2];
            o.w = acc[i][3] + bv[3];
            *(float4*)(out + (size_t)(s0 + row0 + i) * HDIM + col0) = o;
        }
    }
}

// ---------- fallback: round-1 fused kernel (used only if ws too small) ----------
__global__ __launch_bounds__(256)
void fused_pool_mlp(const float* __restrict__ x, const int* __restrict__ batch,
                    const float* __restrict__ W1, const float* __restrict__ b1,
                    const float* __restrict__ W2, const float* __restrict__ b2,
                    float* __restrict__ out, int N)
{
    const int s = blockIdx.x, tid = threadIdx.x;
    const int wave = tid >> 6, lane = tid & 63;
    __shared__ int s_r0, s_r1;
    if (tid == 0) {
        int lo = 0, hi = N;
        while (lo < hi) { int m = (lo + hi) >> 1; if (batch[m] < s)     lo = m + 1; else hi = m; }
        s_r0 = lo; hi = N;
        while (lo < hi) { int m = (lo + hi) >> 1; if (batch[m] < s + 1) lo = m + 1; else hi = m; }
        s_r1 = lo;
    }
    __syncthreads();
    const int r0 = s_r0, r1 = s_r1;
    float4 a0 = make_float4(0.f,0.f,0.f,0.f), a1 = a0;
    int r = r0 + wave;
    for (; r + 4 < r1; r += 8) {
        const float4 v0 = *(const float4*)(x + (size_t)r       * HDIM + lane * 4);
        const float4 v1 = *(const float4*)(x + (size_t)(r + 4) * HDIM + lane * 4);
        a0.x += v0.x; a0.y += v0.y; a0.z += v0.z; a0.w += v0.w;
        a1.x += v1.x; a1.y += v1.y; a1.z += v1.z; a1.w += v1.w;
    }
    if (r < r1) {
        const float4 v0 = *(const float4*)(x + (size_t)r * HDIM + lane * 4);
        a0.x += v0.x; a0.y += v0.y; a0.z += v0.z; a0.w += v0.w;
    }
    a0.x += a1.x; a0.y += a1.y; a0.z += a1.z; a0.w += a1.w;
    __shared__ float4 part4[4][64];
    __shared__ float pooled[HDIM];
    __shared__ float hbuf[HDIM];
    part4[wave][lane] = a0;
    __syncthreads();
    const float* pf = (const float*)part4;
    float sum = (pf[tid] + pf[256 + tid]) + (pf[512 + tid] + pf[768 + tid]);
    const int cnt = r1 - r0;
    pooled[tid] = sum / (float)(cnt > 1 ? cnt : 1);
    __syncthreads();
    float c0 = 0.f, c1 = 0.f, c2 = 0.f, c3 = 0.f;
    for (int k = 0; k < HDIM; k += 4) {
        c0 = fmaf(pooled[k + 0], W1[(k + 0) * HDIM + tid], c0);
        c1 = fmaf(pooled[k + 1], W1[(k + 1) * HDIM + tid], c1);
        c2 = fmaf(pooled[k + 2], W1[(k + 2) * HDIM + tid], c2);
        c3 = fmaf(pooled[k + 3], W1[(k + 3) * HDIM + tid], c3);
    }
    const float z = (c0 + c1) + (c2 + c3) + b1[tid];
    hbuf[tid] = gelu_exact(z);
    __syncthreads();
    c0 = c1 = c2 = c3 = 0.f;
    for (int k = 0; k < HDIM; k += 4) {
        c0 = fmaf(hbuf[k + 0], W2[(k + 0) * HDIM + tid], c0);
        c1 = fmaf(hbuf[k + 1], W2[(k + 1) * HDIM + tid], c1);
        c2 = fmaf(hbuf[k + 2], W2[(k + 2) * HDIM + tid], c2);
        c3 = fmaf(hbuf[k + 3], W2[(k + 3) * HDIM + tid], c3);
    }
    out[(size_t)s * HDIM + tid] = (c0 + c1) + (c2 + c3) + b2[tid];
}

extern "C" void kernel_launch(void* const* d_in, const int* in_sizes, int n_in,
                              void* d_out, int out_size, void* d_ws, size_t ws_size,
                              hipStream_t stream) {
    // setup_inputs order: x, edge_index, edge_type, batch, W1, b1, W2, b2
    const float* x     = (const float*)d_in[0];
    const int*   batch = (const int*)  d_in[3];
    const float* W1    = (const float*)d_in[4];
    const float* b1    = (const float*)d_in[5];
    const float* W2    = (const float*)d_in[6];
    const float* b2    = (const float*)d_in[7];
    float* out = (float*)d_out;
    const int N = in_sizes[3];   // 1048576 rows

    const size_t pooled_bytes = (size_t)NSEG * HDIM * sizeof(float);
    const size_t offs_bytes   = (size_t)(NSEG + 1) * sizeof(int);

    if (ws_size >= pooled_bytes + offs_bytes) {
        float* pooled = (float*)d_ws;
        int*   offs   = (int*)((char*)d_ws + pooled_bytes);
        hipLaunchKernelGGL(seg_offsets_kernel, dim3((NSEG + 256) / 256), dim3(256), 0, stream,
                           batch, offs, N);
        hipLaunchKernelGGL(pool_kernel, dim3(NSEG), dim3(256), 0, stream,
                           x, offs, pooled);
        hipLaunchKernelGGL(mlp_kernel, dim3(NSEG / SPB), dim3(256), 0, stream,
                           pooled, W1, b1, W2, b2, out);
    } else {
        hipLaunchKernelGGL(fused_pool_mlp, dim3(NSEG), dim3(256), 0, stream,
                           x, batch, W1, b1, W2, b2, out, N);
    }
}

// Round 4
// 201.284 us; speedup vs baseline: 1.2616x; 1.2205x over previous
//
#include <hip/hip_runtime.h>
#include <math.h>

#define NSEG 4096
#define HDIM 256
#define SPB  16   // segments per MLP block

typedef float f32x4 __attribute__((ext_vector_type(4)));

__device__ __forceinline__ float gelu_exact(float z) {
    return 0.5f * z * (1.0f + erff(z * 0.7071067811865476f));
}

// ---------- kernel 1: offs[i] = lower_bound(batch, i), i in [0, NSEG] ----------
__global__ __launch_bounds__(256)
void seg_offsets_kernel(const int* __restrict__ batch, int* __restrict__ offs, int N) {
    int i = blockIdx.x * 256 + threadIdx.x;
    if (i > NSEG) return;
    int lo = 0, hi = N;
    while (lo < hi) { int m = (lo + hi) >> 1; if (batch[m] < i) lo = m + 1; else hi = m; }
    offs[i] = lo;
}

// ---------- kernel 2: pooled[s][:] = mean of x rows [offs[s], offs[s+1]) ----------
// One block/segment, 4 waves; wave w owns rows r0+w, r0+w+4, ...
// 8-deep unroll => 8 x 16B loads in flight per lane; nontemporal (streaming,
// no reuse -> don't fight L2/L3 for residency).
__global__ __launch_bounds__(256)
void pool_kernel(const float* __restrict__ x, const int* __restrict__ offs,
                 float* __restrict__ pooled) {
    const int s    = blockIdx.x;
    const int tid  = threadIdx.x;
    const int wave = tid >> 6;
    const int lane = tid & 63;
    const int r0 = offs[s], r1 = offs[s + 1];
    const float* colp = x + (size_t)lane * 4;

    f32x4 acc[8];
    #pragma unroll
    for (int u = 0; u < 8; ++u) acc[u] = (f32x4)(0.f);

    int r = r0 + wave;
    // main loop: 8 rows per wave per iteration (block advances 32 rows)
    for (; r + 28 < r1; r += 32) {
        #pragma unroll
        for (int u = 0; u < 8; ++u) {
            const f32x4 v = __builtin_nontemporal_load(
                reinterpret_cast<const f32x4*>(colp + (size_t)(r + 4 * u) * HDIM));
            acc[u] += v;
        }
    }
    for (; r < r1; r += 4) {
        const f32x4 v = __builtin_nontemporal_load(
            reinterpret_cast<const f32x4*>(colp + (size_t)r * HDIM));
        acc[0] += v;
    }
    // pairwise tree combine
    #pragma unroll
    for (int u = 0; u < 4; ++u) acc[u] += acc[u + 4];
    acc[0] += acc[2];
    acc[1] += acc[3];
    acc[0] += acc[1];

    __shared__ float part[4][HDIM];
    *reinterpret_cast<f32x4*>(&part[wave][lane * 4]) = acc[0];
    __syncthreads();
    float sum = (part[0][tid] + part[1][tid]) + (part[2][tid] + part[3][tid]);
    const int cnt = r1 - r0;
    pooled[(size_t)s * HDIM + tid] = sum / (float)(cnt > 1 ? cnt : 1);
}

// ---------- kernel 3: out = gelu(P @ W1 + b1) @ W2 + b2, 16 segments/block ----------
__global__ __launch_bounds__(256)
void mlp_kernel(const float* __restrict__ pooled,
                const float* __restrict__ W1, const float* __restrict__ b1,
                const float* __restrict__ W2, const float* __restrict__ b2,
                float* __restrict__ out) {
    const int s0   = blockIdx.x * SPB;
    const int tid  = threadIdx.x;
    const int row0 = (tid >> 6) * 4;   // wave -> 4 rows
    const int col0 = (tid & 63) * 4;   // lane -> 4 cols

    __shared__ float P[SPB][HDIM];
    __shared__ float Hs[SPB][HDIM];

    #pragma unroll
    for (int i = 0; i < SPB; ++i)
        P[i][tid] = pooled[(size_t)(s0 + i) * HDIM + tid];
    __syncthreads();

    // ---- layer 1
    float acc[4][4];
    #pragma unroll
    for (int i = 0; i < 4; ++i)
        #pragma unroll
        for (int j = 0; j < 4; ++j) acc[i][j] = 0.f;

    for (int k = 0; k < HDIM; k += 4) {
        const float4 w0 = *(const float4*)(W1 + (size_t)(k + 0) * HDIM + col0);
        const float4 w1 = *(const float4*)(W1 + (size_t)(k + 1) * HDIM + col0);
        const float4 w2 = *(const float4*)(W1 + (size_t)(k + 2) * HDIM + col0);
        const float4 w3 = *(const float4*)(W1 + (size_t)(k + 3) * HDIM + col0);
        #pragma unroll
        for (int i = 0; i < 4; ++i) {
            const float4 p = *(const float4*)(&P[row0 + i][k]);   // wave-broadcast
            acc[i][0] = fmaf(p.x, w0.x, acc[i][0]); acc[i][1] = fmaf(p.x, w0.y, acc[i][1]);
            acc[i][2] = fmaf(p.x, w0.z, acc[i][2]); acc[i][3] = fmaf(p.x, w0.w, acc[i][3]);
            acc[i][0] = fmaf(p.y, w1.x, acc[i][0]); acc[i][1] = fmaf(p.y, w1.y, acc[i][1]);
            acc[i][2] = fmaf(p.y, w1.z, acc[i][2]); acc[i][3] = fmaf(p.y, w1.w, acc[i][3]);
            acc[i][0] = fmaf(p.z, w2.x, acc[i][0]); acc[i][1] = fmaf(p.z, w2.y, acc[i][1]);
            acc[i][2] = fmaf(p.z, w2.z, acc[i][2]); acc[i][3] = fmaf(p.z, w2.w, acc[i][3]);
            acc[i][0] = fmaf(p.w, w3.x, acc[i][0]); acc[i][1] = fmaf(p.w, w3.y, acc[i][1]);
            acc[i][2] = fmaf(p.w, w3.z, acc[i][2]); acc[i][3] = fmaf(p.w, w3.w, acc[i][3]);
        }
    }
    {
        const float4 bb = *(const float4*)(b1 + col0);
        const float bv[4] = {bb.x, bb.y, bb.z, bb.w};
        #pragma unroll
        for (int i = 0; i < 4; ++i) {
            float4 h;
            h.x = gelu_exact(acc[i][0] + bv[0]);
            h.y = gelu_exact(acc[i][1] + bv[1]);
            h.z = gelu_exact(acc[i][2] + bv[2]);
            h.w = gelu_exact(acc[i][3] + bv[3]);
            *(float4*)&Hs[row0 + i][col0] = h;
        }
    }
    __syncthreads();

    // ---- layer 2
    #pragma unroll
    for (int i = 0; i < 4; ++i)
        #pragma unroll
        for (int j = 0; j < 4; ++j) acc[i][j] = 0.f;

    for (int k = 0; k < HDIM; k += 4) {
        const float4 w0 = *(const float4*)(W2 + (size_t)(k + 0) * HDIM + col0);
        const float4 w1 = *(const float4*)(W2 + (size_t)(k + 1) * HDIM + col0);
        const float4 w2 = *(const float4*)(W2 + (size_t)(k + 2) * HDIM + col0);
        const float4 w3 = *(const float4*)(W2 + (size_t)(k + 3) * HDIM + col0);
        #pragma unroll
        for (int i = 0; i < 4; ++i) {
            const float4 p = *(const float4*)(&Hs[row0 + i][k]);
            acc[i][0] = fmaf(p.x, w0.x, acc[i][0]); acc[i][1] = fmaf(p.x, w0.y, acc[i][1]);
            acc[i][2] = fmaf(p.x, w0.z, acc[i][2]); acc[i][3] = fmaf(p.x, w0.w, acc[i][3]);
            acc[i][0] = fmaf(p.y, w1.x, acc[i][0]); acc[i][1] = fmaf(p.y, w1.y, acc[i][1]);
            acc[i][2] = fmaf(p.y, w1.z, acc[i][2]); acc[i][3] = fmaf(p.y, w1.w, acc[i][3]);
            acc[i][0] = fmaf(p.z, w2.x, acc[i][0]); acc[i][1] = fmaf(p.z, w2.y, acc[i][1]);
            acc[i][2] = fmaf(p.z, w2.z, acc[i][2]); acc[i][3] = fmaf(p.z, w2.w, acc[i][3]);
            acc[i][0] = fmaf(p.w, w3.x, acc[i][0]); acc[i][1] = fmaf(p.w, w3.y, acc[i][1]);
            acc[i][2] = fmaf(p.w, w3.z, acc[i][2]); acc[i][3] = fmaf(p.w, w3.w, acc[i][3]);
        }
    }
    {
        const float4 bb = *(const float4*)(b2 + col0);
        const float bv[4] = {bb.x, bb.y, bb.z, bb.w};
        #pragma unroll
        for (int i = 0; i < 4; ++i) {
            float4 o;
            o.x = acc[i][0] + bv[0];
            o.y = acc[i][1] + bv[1];
            o.z = acc[i][2] + bv[2];
            o.w = acc[i][3] + bv[3];
            *(float4*)(out + (size_t)(s0 + row0 + i) * HDIM + col0) = o;
        }
    }
}

// ---------- fallback: fused kernel (used only if ws too small) ----------
__global__ __launch_bounds__(256)
void fused_pool_mlp(const float* __restrict__ x, const int* __restrict__ batch,
                    const float* __restrict__ W1, const float* __restrict__ b1,
                    const float* __restrict__ W2, const float* __restrict__ b2,
                    float* __restrict__ out, int N)
{
    const int s = blockIdx.x, tid = threadIdx.x;
    const int wave = tid >> 6, lane = tid & 63;
    __shared__ int s_r0, s_r1;
    if (tid == 0) {
        int lo = 0, hi = N;
        while (lo < hi) { int m = (lo + hi) >> 1; if (batch[m] < s)     lo = m + 1; else hi = m; }
        s_r0 = lo; hi = N;
        while (lo < hi) { int m = (lo + hi) >> 1; if (batch[m] < s + 1) lo = m + 1; else hi = m; }
        s_r1 = lo;
    }
    __syncthreads();
    const int r0 = s_r0, r1 = s_r1;
    float4 a0 = make_float4(0.f,0.f,0.f,0.f), a1 = a0;
    int r = r0 + wave;
    for (; r + 4 < r1; r += 8) {
        const float4 v0 = *(const float4*)(x + (size_t)r       * HDIM + lane * 4);
        const float4 v1 = *(const float4*)(x + (size_t)(r + 4) * HDIM + lane * 4);
        a0.x += v0.x; a0.y += v0.y; a0.z += v0.z; a0.w += v0.w;
        a1.x += v1.x; a1.y += v1.y; a1.z += v1.z; a1.w += v1.w;
    }
    if (r < r1) {
        const float4 v0 = *(const float4*)(x + (size_t)r * HDIM + lane * 4);
        a0.x += v0.x; a0.y += v0.y; a0.z += v0.z; a0.w += v0.w;
    }
    a0.x += a1.x; a0.y += a1.y; a0.z += a1.z; a0.w += a1.w;
    __shared__ float4 part4[4][64];
    __shared__ float pooled[HDIM];
    __shared__ float hbuf[HDIM];
    part4[wave][lane] = a0;
    __syncthreads();
    const float* pf = (const float*)part4;
    float sum = (pf[tid] + pf[256 + tid]) + (pf[512 + tid] + pf[768 + tid]);
    const int cnt = r1 - r0;
    pooled[tid] = sum / (float)(cnt > 1 ? cnt : 1);
    __syncthreads();
    float c0 = 0.f, c1 = 0.f, c2 = 0.f, c3 = 0.f;
    for (int k = 0; k < HDIM; k += 4) {
        c0 = fmaf(pooled[k + 0], W1[(k + 0) * HDIM + tid], c0);
        c1 = fmaf(pooled[k + 1], W1[(k + 1) * HDIM + tid], c1);
        c2 = fmaf(pooled[k + 2], W1[(k + 2) * HDIM + tid], c2);
        c3 = fmaf(pooled[k + 3], W1[(k + 3) * HDIM + tid], c3);
    }
    const float z = (c0 + c1) + (c2 + c3) + b1[tid];
    hbuf[tid] = gelu_exact(z);
    __syncthreads();
    c0 = c1 = c2 = c3 = 0.f;
    for (int k = 0; k < HDIM; k += 4) {
        c0 = fmaf(hbuf[k + 0], W2[(k + 0) * HDIM + tid], c0);
        c1 = fmaf(hbuf[k + 1], W2[(k + 1) * HDIM + tid], c1);
        c2 = fmaf(hbuf[k + 2], W2[(k + 2) * HDIM + tid], c2);
        c3 = fmaf(hbuf[k + 3], W2[(k + 3) * HDIM + tid], c3);
    }
    out[(size_t)s * HDIM + tid] = (c0 + c1) + (c2 + c3) + b2[tid];
}

extern "C" void kernel_launch(void* const* d_in, const int* in_sizes, int n_in,
                              void* d_out, int out_size, void* d_ws, size_t ws_size,
                              hipStream_t stream) {
    // setup_inputs order: x, edge_index, edge_type, batch, W1, b1, W2, b2
    const float* x     = (const float*)d_in[0];
    const int*   batch = (const int*)  d_in[3];
    const float* W1    = (const float*)d_in[4];
    const float* b1    = (const float*)d_in[5];
    const float* W2    = (const float*)d_in[6];
    const float* b2    = (const float*)d_in[7];
    float* out = (float*)d_out;
    const int N = in_sizes[3];   // 1048576 rows

    const size_t pooled_bytes = (size_t)NSEG * HDIM * sizeof(float);
    const size_t offs_bytes   = (size_t)(NSEG + 1) * sizeof(int);

    if (ws_size >= pooled_bytes + offs_bytes) {
        float* pooled = (float*)d_ws;
        int*   offs   = (int*)((char*)d_ws + pooled_bytes);
        hipLaunchKernelGGL(seg_offsets_kernel, dim3((NSEG + 256) / 256), dim3(256), 0, stream,
                           batch, offs, N);
        hipLaunchKernelGGL(pool_kernel, dim3(NSEG), dim3(256), 0, stream,
                           x, offs, pooled);
        hipLaunchKernelGGL(mlp_kernel, dim3(NSEG / SPB), dim3(256), 0, stream,
                           pooled, W1, b1, W2, b2, out);
    } else {
        hipLaunchKernelGGL(fused_pool_mlp, dim3(NSEG), dim3(256), 0, stream,
                           x, batch, W1, b1, W2, b2, out, N);
    }
}